// Round 1
// 175.156 us; speedup vs baseline: 1.0564x; 1.0564x over previous
//
#include <hip/hip_runtime.h>
#include <math.h>

#define S_LEN  2048
#define BATCH  2
#define DM     1024
#define NHEAD  16
#define DHEAD  64
#define WIN    256
#define MROWS  4096

#define KP   72     // bf16 LDS row stride for attn K/V tiles
#define PPAD 68     // f32 LDS row stride for attn P

// gemm_qkv tile geometry (R12)
#define BM 256
#define BN 192
#define BK 64

typedef __attribute__((ext_vector_type(8))) short bf16x8;
typedef __attribute__((ext_vector_type(4))) float f32x4;

__device__ __forceinline__ unsigned short f2b(float f) {   // RNE
    unsigned int u = __float_as_uint(f);
    return (unsigned short)((u + 0x7fffu + ((u >> 16) & 1u)) >> 16);
}
__device__ __forceinline__ void gld16(const void* g, void* l) {
    __builtin_amdgcn_global_load_lds(
        (const __attribute__((address_space(1))) void*)g,
        (__attribute__((address_space(3))) void*)l, 16, 0, 0);
}
__device__ __forceinline__ bf16x8 pack8(float4 a, float4 b) {
    bf16x8 r;
    r[0] = (short)f2b(a.x); r[1] = (short)f2b(a.y);
    r[2] = (short)f2b(a.z); r[3] = (short)f2b(a.w);
    r[4] = (short)f2b(b.x); r[5] = (short)f2b(b.y);
    r[6] = (short)f2b(b.z); r[7] = (short)f2b(b.w);
    return r;
}

// ---------------------------------------------------------------------------
// fp32 -> bf16 convert (x): 4M elems, 4/thread
// ---------------------------------------------------------------------------
__global__ __launch_bounds__(256)
void cvtx(const float* __restrict__ x, unsigned short* __restrict__ xb)
{
    const int i = (blockIdx.x * 256 + threadIdx.x) * 4;
    float4 f = *(const float4*)(x + i);
    ushort4 o; o.x = f2b(f.x); o.y = f2b(f.y); o.z = f2b(f.z); o.w = f2b(f.w);
    *(ushort4*)(xb + i) = o;
}

// ---------------------------------------------------------------------------
// 4x fused: W (K x N fp32) -> W^T (N x K bf16)
// ---------------------------------------------------------------------------
__global__ __launch_bounds__(256)
void twcvt4(const float* __restrict__ W0, const float* __restrict__ W1,
            const float* __restrict__ W2, const float* __restrict__ W3,
            unsigned short* __restrict__ T0, unsigned short* __restrict__ T1,
            unsigned short* __restrict__ T2, unsigned short* __restrict__ T3)
{
    const int zz = blockIdx.z;
    const float* W = (zz == 0) ? W0 : (zz == 1) ? W1 : (zz == 2) ? W2 : W3;
    unsigned short* WT = (zz == 0) ? T0 : (zz == 1) ? T1 : (zz == 2) ? T2 : T3;

    __shared__ float t32[32][33];
    const int bx = blockIdx.x * 32;
    const int by = blockIdx.y * 32;
    const int c  = threadIdx.x & 31;
    const int r0 = threadIdx.x >> 5;
#pragma unroll
    for (int p = 0; p < 4; ++p)
        t32[r0 + 8 * p][c] = W[(size_t)(by + r0 + 8 * p) * DM + bx + c];
    __syncthreads();
#pragma unroll
    for (int p = 0; p < 4; ++p)
        WT[(size_t)(bx + r0 + 8 * p) * DM + by + c] = f2b(t32[c][r0 + 8 * p]);
}

// ---------------------------------------------------------------------------
// R12: fused QKV projection, 256x192 tile, BK=64, 8 waves (2Mx4N), 512 thr.
// Double-buffered LDS (112 KB), 4 phases per K-tile, counted vmcnt (never 0
// in the loop), raw s_barrier (no __syncthreads -> no vmcnt(0) drain),
// setprio(1) around MFMA clusters.
//
// LDS swizzle: within a 128B row, 16B chunk p holds global chunk p^(row&7);
// staging pre-swizzles the per-lane GLOBAL source (LDS dest stays linear,
// required by global_load_lds), reads XOR the chunk index. Max 2-way bank
// aliasing (free).
//
// Staging ledger (stage tile kt+1 into buf[cur^1] during iter kt):
//   p0 issues {B0,B1}  p1 issues {B2,A0}  p2 issues {A2,A1}  p3 issues {A3}
//   iter kt+1 p0/p1 read  B0..B2, A0, A2  -> guaranteed by vmcnt(2) @ p3 end
//   iter kt+1 p2/p3 read  A1, A3          -> guaranteed by vmcnt(4) @ p1 end
// (only VMEM ops in the loop are these 7 loads -> counts are exact)
// ---------------------------------------------------------------------------
__global__ __launch_bounds__(512, 2)
void gemm_qkv(const unsigned short* __restrict__ A,
              const unsigned short* __restrict__ BT,
              const float* __restrict__ b0,
              const float* __restrict__ b1,
              const float* __restrict__ b2,
              const float* __restrict__ beta,
              unsigned short* __restrict__ Cb)
{
    __shared__ unsigned short Ab[2][BM * BK];   // 2 x 32 KB
    __shared__ unsigned short Bb[2][BN * BK];   // 2 x 24 KB

    const int t   = threadIdx.x;
    const int ln  = t & 63;
    const int wv  = t >> 6;          // 0..7
    const int wr  = wv >> 2;         // 0..1  -> 128-row half
    const int wc  = wv & 3;          // 0..3  -> 48-col slice
    const int m16 = ln & 15;
    const int g   = ln >> 4;         // 0..3
    const int sw  = m16 & 7;         // read-side swizzle key

    const int rowBase = blockIdx.y * BM;
    const int colBase = blockIdx.x * BN;

    // staging: thread t covers row (t>>3) of a 64-row chunk, 16B at a
    // pre-swizzled global col-chunk; LDS dest is linear (t*16B).
    const int sr  = t >> 3;                   // 0..63
    const int scx = (t & 7) ^ (sr & 7);       // global col-chunk to fetch
    const size_t gOff = (size_t)sr * DM + scx * 8;
    const int    ldOff = t * 8;               // shorts (t*16 bytes)

    f32x4 acc[8][3];
#pragma unroll
    for (int u = 0; u < 8; ++u)
#pragma unroll
        for (int v = 0; v < 3; ++v)
            acc[u][v] = (f32x4){0.f, 0.f, 0.f, 0.f};

    // prologue: stage K-tile 0 into buffer 0, full drain once
    {
        const unsigned short* a0 = A  + (size_t)rowBase * DM + gOff;
        const unsigned short* bt = BT + (size_t)colBase * DM + gOff;
#pragma unroll
        for (int cb = 0; cb < 3; ++cb)
            gld16(bt + (size_t)cb * 64 * DM, &Bb[0][cb * 4096 + ldOff]);
#pragma unroll
        for (int ca = 0; ca < 4; ++ca)
            gld16(a0 + (size_t)ca * 64 * DM, &Ab[0][ca * 4096 + ldOff]);
        asm volatile("s_waitcnt vmcnt(0)" ::: "memory");
        __builtin_amdgcn_s_barrier();
    }

    bf16x8 af[4][2], bfr[2][2];

    for (int kt = 0; kt < DM / BK; ++kt) {
        const int cur = kt & 1;
        const unsigned short* Ac = Ab[cur];
        const unsigned short* Bc = Bb[cur];
        unsigned short* An = Ab[cur ^ 1];
        unsigned short* Bn = Bb[cur ^ 1];
        const bool hn = (kt < DM / BK - 1);
        const unsigned short* aS = A  + (size_t)rowBase * DM + (kt + 1) * BK + gOff;
        const unsigned short* bS = BT + (size_t)colBase * DM + (kt + 1) * BK + gOff;

        // ---------------- phase 0: rows wr*128+0..63, v=0..1 ----------------
#pragma unroll
        for (int u = 0; u < 4; ++u) {
            const int ro = (wr * 128 + u * 16 + m16) * BK;
#pragma unroll
            for (int kk = 0; kk < 2; ++kk)
                af[u][kk] = *(const bf16x8*)&Ac[ro + (((kk << 2) | g) ^ sw) * 8];
        }
#pragma unroll
        for (int v = 0; v < 2; ++v) {
            const int ro = (wc * 48 + v * 16 + m16) * BK;
#pragma unroll
            for (int kk = 0; kk < 2; ++kk)
                bfr[v][kk] = *(const bf16x8*)&Bc[ro + (((kk << 2) | g) ^ sw) * 8];
        }
        if (hn) {
            gld16(bS,                      &Bn[ldOff]);            // B0
            gld16(bS + (size_t)64 * DM,    &Bn[4096 + ldOff]);     // B1
        }
        __builtin_amdgcn_s_barrier();
        __builtin_amdgcn_s_setprio(1);
#pragma unroll
        for (int u = 0; u < 4; ++u)
#pragma unroll
            for (int v = 0; v < 2; ++v) {
                acc[u][v] = __builtin_amdgcn_mfma_f32_16x16x32_bf16(
                    af[u][0], bfr[v][0], acc[u][v], 0, 0, 0);
                acc[u][v] = __builtin_amdgcn_mfma_f32_16x16x32_bf16(
                    af[u][1], bfr[v][1], acc[u][v], 0, 0, 0);
            }
        __builtin_amdgcn_s_setprio(0);
        __builtin_amdgcn_s_barrier();

        // ---------------- phase 1: rows wr*128+0..63, v=2 -------------------
        {
            const int ro = (wc * 48 + 32 + m16) * BK;
#pragma unroll
            for (int kk = 0; kk < 2; ++kk)
                bfr[0][kk] = *(const bf16x8*)&Bc[ro + (((kk << 2) | g) ^ sw) * 8];
        }
        if (hn) {
            gld16(bS + (size_t)128 * DM,   &Bn[2 * 4096 + ldOff]); // B2
            gld16(aS,                      &An[ldOff]);            // A0
        }
        __builtin_amdgcn_s_barrier();
        __builtin_amdgcn_s_setprio(1);
#pragma unroll
        for (int u = 0; u < 4; ++u) {
            acc[u][2] = __builtin_amdgcn_mfma_f32_16x16x32_bf16(
                af[u][0], bfr[0][0], acc[u][2], 0, 0, 0);
            acc[u][2] = __builtin_amdgcn_mfma_f32_16x16x32_bf16(
                af[u][1], bfr[0][1], acc[u][2], 0, 0, 0);
        }
        __builtin_amdgcn_s_setprio(0);
        asm volatile("s_waitcnt vmcnt(4)" ::: "memory");  // A1,A3 of cur landed
        __builtin_amdgcn_s_barrier();

        // ---------------- phase 2: rows wr*128+64..127, v=0..1 --------------
#pragma unroll
        for (int u = 0; u < 4; ++u) {
            const int ro = (wr * 128 + 64 + u * 16 + m16) * BK;
#pragma unroll
            for (int kk = 0; kk < 2; ++kk)
                af[u][kk] = *(const bf16x8*)&Ac[ro + (((kk << 2) | g) ^ sw) * 8];
        }
#pragma unroll
        for (int v = 0; v < 2; ++v) {
            const int ro = (wc * 48 + v * 16 + m16) * BK;
#pragma unroll
            for (int kk = 0; kk < 2; ++kk)
                bfr[v][kk] = *(const bf16x8*)&Bc[ro + (((kk << 2) | g) ^ sw) * 8];
        }
        if (hn) {
            gld16(aS + (size_t)128 * DM,   &An[2 * 4096 + ldOff]); // A2 (first!)
            gld16(aS + (size_t)64 * DM,    &An[4096 + ldOff]);     // A1
        }
        __builtin_amdgcn_s_barrier();
        __builtin_amdgcn_s_setprio(1);
#pragma unroll
        for (int u = 0; u < 4; ++u)
#pragma unroll
            for (int v = 0; v < 2; ++v) {
                acc[4 + u][v] = __builtin_amdgcn_mfma_f32_16x16x32_bf16(
                    af[u][0], bfr[v][0], acc[4 + u][v], 0, 0, 0);
                acc[4 + u][v] = __builtin_amdgcn_mfma_f32_16x16x32_bf16(
                    af[u][1], bfr[v][1], acc[4 + u][v], 0, 0, 0);
            }
        __builtin_amdgcn_s_setprio(0);
        __builtin_amdgcn_s_barrier();

        // ---------------- phase 3: rows wr*128+64..127, v=2 -----------------
        {
            const int ro = (wc * 48 + 32 + m16) * BK;
#pragma unroll
            for (int kk = 0; kk < 2; ++kk)
                bfr[0][kk] = *(const bf16x8*)&Bc[ro + (((kk << 2) | g) ^ sw) * 8];
        }
        if (hn) {
            gld16(aS + (size_t)192 * DM,   &An[3 * 4096 + ldOff]); // A3
        }
        __builtin_amdgcn_s_barrier();
        __builtin_amdgcn_s_setprio(1);
#pragma unroll
        for (int u = 0; u < 4; ++u) {
            acc[4 + u][2] = __builtin_amdgcn_mfma_f32_16x16x32_bf16(
                af[u][0], bfr[0][0], acc[4 + u][2], 0, 0, 0);
            acc[4 + u][2] = __builtin_amdgcn_mfma_f32_16x16x32_bf16(
                af[u][1], bfr[0][1], acc[4 + u][2], 0, 0, 0);
        }
        __builtin_amdgcn_s_setprio(0);
        asm volatile("s_waitcnt vmcnt(2)" ::: "memory");  // next B*,A0,A2 landed
        __builtin_amdgcn_s_barrier();
    }

    // epilogue — identical math to the proven kernel; sec per fragment since
    // a 192-wide tile can cross the q/k/v 1024-col boundaries (wave-uniform).
    const int q4 = g * 4;
#pragma unroll
    for (int v = 0; v < 3; ++v) {
        const int col = colBase + wc * 48 + v * 16 + m16;
        const int sec = col >> 10;
        const int h   = (col >> 6) & (NHEAD - 1);
        const int dh  = col & 63;
        if (sec < 2) {
            const float bi = (sec == 0 ? b0 : b1)[col & (DM - 1)];
            const float sc = (sec == 0) ? 0.125f * __expf(-beta[h]) : 1.0f;
            unsigned short* base = Cb + (size_t)sec * MROWS * DM;
#pragma unroll
            for (int u = 0; u < 8; ++u)
#pragma unroll
                for (int r = 0; r < 4; ++r) {
                    const int row = rowBase + wr * 128 + u * 16 + q4 + r;
                    const int s = row >> 1, bb = row & 1;
                    const int z = bb * NHEAD + h;
                    base[((size_t)z * S_LEN + s) * DHEAD + dh] =
                        f2b((acc[u][v][r] + bi) * sc);
                }
        } else {
            unsigned short* vtb = Cb + (size_t)2 * MROWS * DM;
            const float bi = b2[col & (DM - 1)];
#pragma unroll
            for (int u = 0; u < 8; ++u) {
                const int row0 = rowBase + wr * 128 + u * 16 + q4;
                const int s0   = row0 >> 1;
                ushort2 p0, p1;
                p0.x = f2b(acc[u][v][0] + bi);   // bb=0, s0
                p0.y = f2b(acc[u][v][2] + bi);   // bb=0, s0+1
                p1.x = f2b(acc[u][v][1] + bi);   // bb=1, s0
                p1.y = f2b(acc[u][v][3] + bi);   // bb=1, s0+1
                *(ushort2*)(vtb + ((size_t)(h * DHEAD + dh) * S_LEN + s0)) = p0;
                *(ushort2*)(vtb + ((size_t)((NHEAD + h) * DHEAD + dh) * S_LEN + s0)) = p1;
            }
        }
    }
}

// ---------------------------------------------------------------------------
// Output projection: 128x64 tile (512 blocks = 2/CU), BK=32, 4 waves
// as 2x2 of 64x32 (R10-proven).
// ---------------------------------------------------------------------------
__global__ __launch_bounds__(256)
void gemm_out(const unsigned short* __restrict__ A,
              const unsigned short* __restrict__ BT,
              const float* __restrict__ bias,
              float* __restrict__ Cf)
{
    __shared__ unsigned short As[128 * 32];   // 8 KB
    __shared__ unsigned short Bs[64 * 32];    // 4 KB

    const int t  = threadIdx.x;
    const int wv = t >> 6, ln = t & 63;
    const int rowBase = blockIdx.y * 128;
    const int colBase = blockIdx.x * 64;

    const int m16 = ln & 15, g = ln >> 4;
    const int wr = wv >> 1, wc = wv & 1;
    const int swz = (m16 >> 1) & 3;

    const int lr = ln >> 2;
    const int lq = (ln & 3) ^ ((lr >> 1) & 3);
    const unsigned short* ga = A  + (size_t)(rowBase + wv * 16 + lr) * DM + lq * 8;
    const unsigned short* gb = BT + (size_t)(colBase + wv * 16 + lr) * DM + lq * 8;
    unsigned short* la0 = As + wv * 512;
    unsigned short* la1 = la0 + 2048;         // rows 64..127
    unsigned short* lb  = Bs + wv * 512;      // 64 rows total

    f32x4 acc[4][2];
#pragma unroll
    for (int u = 0; u < 4; ++u)
#pragma unroll
        for (int v = 0; v < 2; ++v)
            acc[u][v] = (f32x4){0.f, 0.f, 0.f, 0.f};

    for (int kb = 0; kb < DM; kb += 32) {
        gld16(ga + kb, la0);
        gld16(ga + (size_t)64 * DM + kb, la1);
        gld16(gb + kb, lb);
        __syncthreads();

        bf16x8 af[4], bfr[2];
#pragma unroll
        for (int u = 0; u < 4; ++u)
            af[u] = *(const bf16x8*)&As[(wr * 64 + u * 16 + m16) * 32 + ((g ^ swz) * 8)];
#pragma unroll
        for (int v = 0; v < 2; ++v)
            bfr[v] = *(const bf16x8*)&Bs[(wc * 32 + v * 16 + m16) * 32 + ((g ^ swz) * 8)];
#pragma unroll
        for (int u = 0; u < 4; ++u)
#pragma unroll
            for (int v = 0; v < 2; ++v)
                acc[u][v] = __builtin_amdgcn_mfma_f32_16x16x32_bf16(
                    af[u], bfr[v], acc[u][v], 0, 0, 0);
        __syncthreads();
    }

    const int q4 = g * 4;
#pragma unroll
    for (int v = 0; v < 2; ++v) {
        const int col = colBase + wc * 32 + v * 16 + m16;
        const float bi = bias[col];
#pragma unroll
        for (int u = 0; u < 4; ++u)
#pragma unroll
            for (int r = 0; r < 4; ++r) {
                const int row = rowBase + wr * 64 + u * 16 + q4 + r;
                Cf[(size_t)row * DM + col] = acc[u][v][r] + bi;
            }
    }
}

// ---------------------------------------------------------------------------
// MFMA flash attention, windowed causal + sink — NO online max (R11-proven).
// Scores bounded (|s| <~ 6 after 0.125*exp(-beta) pre-scale) -> plain exp
// is safe in fp32. Sink: l0 = 1 = exp(0). Masked: exp(-1e30) == 0.
// q,k in (z,s,dh); V pre-transposed vt (z,dh,s). All staging b128.
// ---------------------------------------------------------------------------
__global__ __launch_bounds__(256, 4)
void attn_mfma(const unsigned short* __restrict__ q,
               const unsigned short* __restrict__ k,
               const unsigned short* __restrict__ vt,
               unsigned short* __restrict__ ao)
{
    __shared__ unsigned short Ks[64 * KP];   // [key][d]
    __shared__ unsigned short Vs[64 * KP];   // [dh][key]
    __shared__ float Ps[64][PPAD];           // [wave*16 + qrow][key]

    const int t   = threadIdx.x;
    const int wv  = t >> 6, ln = t & 63;
    const int m16 = ln & 15, g = ln >> 4;
    const int z   = blockIdx.y;
    const int q0  = blockIdx.x * 64;
    const size_t zbase = (size_t)z * S_LEN * DHEAD;

    const unsigned short* qrow = q + zbase + (size_t)(q0 + wv * 16 + m16) * DHEAD;
    bf16x8 qf0 = *(const bf16x8*)(qrow + g * 8);
    bf16x8 qf1 = *(const bf16x8*)(qrow + 32 + g * 8);

    f32x4 oacc[4];
#pragma unroll
    for (int v4 = 0; v4 < 4; ++v4) oacc[v4] = (f32x4){0.f, 0.f, 0.f, 0.f};
    float lr[4];
#pragma unroll
    for (int r = 0; r < 4; ++r) lr[r] = 1.f;   // sink: exp(0)

    for (int c = 0; c < 5; ++c) {
        const int kb = q0 - 256 + c * 64;
        if (kb < 0) continue;
        __syncthreads();

        // stage K [64][64] and V^T [64][64], b128 copies
#pragma unroll
        for (int i = 0; i < 2; ++i) {
            const int id  = t + 256 * i;
            const int row = id >> 3;
            const int co  = (id & 7) * 8;
            *(bf16x8*)&Ks[row * KP + co] =
                *(const bf16x8*)(k + zbase + (size_t)(kb + row) * DHEAD + co);
            *(bf16x8*)&Vs[row * KP + co] =
                *(const bf16x8*)(vt + ((size_t)z * DHEAD + row) * S_LEN + kb + co);
        }
        __syncthreads();

        // S = Q K^T
        f32x4 sacc[4];
#pragma unroll
        for (int v4 = 0; v4 < 4; ++v4) {
            sacc[v4] = (f32x4){0.f, 0.f, 0.f, 0.f};
            bf16x8 kf0 = *(const bf16x8*)&Ks[(v4 * 16 + m16) * KP + g * 8];
            sacc[v4] = __builtin_amdgcn_mfma_f32_16x16x32_bf16(qf0, kf0, sacc[v4], 0, 0, 0);
            bf16x8 kf1 = *(const bf16x8*)&Ks[(v4 * 16 + m16) * KP + 32 + g * 8];
            sacc[v4] = __builtin_amdgcn_mfma_f32_16x16x32_bf16(qf1, kf1, sacc[v4], 0, 0, 0);
        }

        // mask + exp + row-sum (no max): P -> LDS
        const bool mhi = (c == 4), mlo = (c == 0);
#pragma unroll
        for (int r = 0; r < 4; ++r) {
            const int ig = q0 + wv * 16 + g * 4 + r;
            float rsum = 0.f;
#pragma unroll
            for (int v4 = 0; v4 < 4; ++v4) {
                const int jg = kb + v4 * 16 + m16;
                float x = sacc[v4][r];
                const bool valid = (!mhi || jg <= ig) && (!mlo || jg >= ig - (WIN - 1));
                x = valid ? x : -1e30f;
                const float pp = __expf(x);     // masked -> exactly 0
                Ps[wv * 16 + g * 4 + r][v4 * 16 + m16] = pp;
                rsum += pp;
            }
#pragma unroll
            for (int off = 1; off < 16; off <<= 1)
                rsum += __shfl_xor(rsum, off, 64);
            lr[r] += rsum;
        }
        __syncthreads();

        // O += P V
        const float* prow = &Ps[wv * 16 + m16][0];
        bf16x8 pf0 = pack8(*(const float4*)(prow + g * 8),
                           *(const float4*)(prow + g * 8 + 4));
        bf16x8 pf1 = pack8(*(const float4*)(prow + 32 + g * 8),
                           *(const float4*)(prow + 32 + g * 8 + 4));
#pragma unroll
        for (int v4 = 0; v4 < 4; ++v4) {
            bf16x8 vf0 = *(const bf16x8*)&Vs[(v4 * 16 + m16) * KP + g * 8];
            oacc[v4] = __builtin_amdgcn_mfma_f32_16x16x32_bf16(pf0, vf0, oacc[v4], 0, 0, 0);
            bf16x8 vf1 = *(const bf16x8*)&Vs[(v4 * 16 + m16) * KP + 32 + g * 8];
            oacc[v4] = __builtin_amdgcn_mfma_f32_16x16x32_bf16(pf1, vf1, oacc[v4], 0, 0, 0);
        }
    }

    const int bb = z >> 4, h = z & 15;
#pragma unroll
    for (int r = 0; r < 4; ++r) {
        const int ig  = q0 + wv * 16 + g * 4 + r;
        const float inv = 1.f / lr[r];
#pragma unroll
        for (int v4 = 0; v4 < 4; ++v4)
            ao[(size_t)(ig * BATCH + bb) * DM + h * DHEAD + v4 * 16 + m16] =
                f2b(oacc[v4][r] * inv);
    }
}

// ---------------------------------------------------------------------------
extern "C" void kernel_launch(void* const* d_in, const int* in_sizes, int n_in,
                              void* d_out, int out_size, void* d_ws, size_t ws_size,
                              hipStream_t stream)
{
    const float* x    = (const float*)d_in[0];
    const float* beta = (const float*)d_in[1];
    const float* Wq   = (const float*)d_in[2];
    const float* bq   = (const float*)d_in[3];
    const float* Wk   = (const float*)d_in[4];
    const float* bk   = (const float*)d_in[5];
    const float* Wv   = (const float*)d_in[6];
    const float* bv   = (const float*)d_in[7];
    const float* Wo   = (const float*)d_in[8];
    const float* bo   = (const float*)d_in[9];
    float* out = (float*)d_out;

    unsigned short* w = (unsigned short*)d_ws;
    const size_t seg = (size_t)MROWS * DM;      // 4M elems
    unsigned short* qb  = w;                    // q (z,s,dh)
    unsigned short* kb  = w + seg;              // k (z,s,dh)
    unsigned short* vtb = w + 2 * seg;          // v^T (z,dh,s) -- direct from QKV
    unsigned short* ab  = w + 3 * seg;          // attn out, row-major
    unsigned short* xb  = w + 4 * seg;          // x bf16
    unsigned short* wtq = w + 5 * seg;          // WqT|WkT|WvT|WoT contiguous
    unsigned short* wtk = wtq + (size_t)DM * DM;
    unsigned short* wtv = wtk + (size_t)DM * DM;
    unsigned short* wto = wtv + (size_t)DM * DM;

    cvtx<<<4096, 256, 0, stream>>>(x, xb);
    twcvt4<<<dim3(32, 32, 4), 256, 0, stream>>>(Wq, Wk, Wv, Wo, wtq, wtk, wtv, wto);

    // fused Q+K+V projection: 256x192 tiles -> 16x16 = 256 blocks (1/CU)
    gemm_qkv<<<dim3(3072 / BN, MROWS / BM), 512, 0, stream>>>(
        xb, wtq, bq, bk, bv, beta, qb);

    attn_mfma<<<dim3(S_LEN / 64, BATCH * NHEAD), 256, 0, stream>>>(qb, kb, vtb, ab);

    // output projection: 128x64 tiles -> 512 blocks (2/CU)
    gemm_out<<<dim3(DM / 64, MROWS / 128), 256, 0, stream>>>(ab, wto, bo, out);
}

// Round 2
// 169.410 us; speedup vs baseline: 1.0922x; 1.0339x over previous
//
#include <hip/hip_runtime.h>
#include <math.h>

#define S_LEN  2048
#define BATCH  2
#define DM     1024
#define NHEAD  16
#define DHEAD  64
#define WIN    256
#define MROWS  4096

#define KP   72     // bf16 LDS row stride for attn K/V tiles
#define PPAD 68     // f32 LDS row stride for attn P

// gemm_qkv tile geometry (R13): 256x192, BK=64, 8 waves as 4M x 2N
#define BM 256
#define BN 192
#define BK 64

// gemm_out tile geometry (R13): 128x128, BK=64, 4 waves as 2x2
#define OM 128
#define ON 128

typedef __attribute__((ext_vector_type(8))) short bf16x8;
typedef __attribute__((ext_vector_type(4))) float f32x4;

__device__ __forceinline__ unsigned short f2b(float f) {   // RNE
    unsigned int u = __float_as_uint(f);
    return (unsigned short)((u + 0x7fffu + ((u >> 16) & 1u)) >> 16);
}
__device__ __forceinline__ void gld16(const void* g, void* l) {
    __builtin_amdgcn_global_load_lds(
        (const __attribute__((address_space(1))) void*)g,
        (__attribute__((address_space(3))) void*)l, 16, 0, 0);
}
__device__ __forceinline__ bf16x8 pack8(float4 a, float4 b) {
    bf16x8 r;
    r[0] = (short)f2b(a.x); r[1] = (short)f2b(a.y);
    r[2] = (short)f2b(a.z); r[3] = (short)f2b(a.w);
    r[4] = (short)f2b(b.x); r[5] = (short)f2b(b.y);
    r[6] = (short)f2b(b.z); r[7] = (short)f2b(b.w);
    return r;
}

// ---------------------------------------------------------------------------
// fp32 -> bf16 convert (x): 4M elems, 4/thread
// ---------------------------------------------------------------------------
__global__ __launch_bounds__(256)
void cvtx(const float* __restrict__ x, unsigned short* __restrict__ xb)
{
    const int i = (blockIdx.x * 256 + threadIdx.x) * 4;
    float4 f = *(const float4*)(x + i);
    ushort4 o; o.x = f2b(f.x); o.y = f2b(f.y); o.z = f2b(f.z); o.w = f2b(f.w);
    *(ushort4*)(xb + i) = o;
}

// ---------------------------------------------------------------------------
// 4x fused: W (K x N fp32) -> W^T (N x K bf16)
// ---------------------------------------------------------------------------
__global__ __launch_bounds__(256)
void twcvt4(const float* __restrict__ W0, const float* __restrict__ W1,
            const float* __restrict__ W2, const float* __restrict__ W3,
            unsigned short* __restrict__ T0, unsigned short* __restrict__ T1,
            unsigned short* __restrict__ T2, unsigned short* __restrict__ T3)
{
    const int zz = blockIdx.z;
    const float* W = (zz == 0) ? W0 : (zz == 1) ? W1 : (zz == 2) ? W2 : W3;
    unsigned short* WT = (zz == 0) ? T0 : (zz == 1) ? T1 : (zz == 2) ? T2 : T3;

    __shared__ float t32[32][33];
    const int bx = blockIdx.x * 32;
    const int by = blockIdx.y * 32;
    const int c  = threadIdx.x & 31;
    const int r0 = threadIdx.x >> 5;
#pragma unroll
    for (int p = 0; p < 4; ++p)
        t32[r0 + 8 * p][c] = W[(size_t)(by + r0 + 8 * p) * DM + bx + c];
    __syncthreads();
#pragma unroll
    for (int p = 0; p < 4; ++p)
        WT[(size_t)(bx + r0 + 8 * p) * DM + by + c] = f2b(t32[c][r0 + 8 * p]);
}

// ---------------------------------------------------------------------------
// R13 gemm_qkv: 256x192, BK=64, 8 waves as 4M x 2N (wave tile 64x96).
// ds_read per wave per K-tile: A 8 + B 12 = 20 b128 (was 28) -> LDS pipe
// (1920 cy/CU/tile) ~ MFMA pipe (1862 cy). Schedule: ONE barrier per K-tile:
//   { kk0 frag reads | issue all 7 staging loads (next tile) | 24 MFMA |
//     kk1 frag reads | 24 MFMA | vmcnt(0) | s_barrier | sched_barrier }
// vmcnt wait has ~2 phases of slack over L2-resident staging (~300 cy).
// Hazards: reads of buf[cur] complete (lgkm) before the end barrier;
// staging into buf[cur^1] only issues after it -> race-free.
// XOR chunk swizzle (chunk ^= row&7) on both staging SOURCE and read addr;
// LDS dest linear (global_load_lds requirement). Bank-conflict-free (R9).
// ---------------------------------------------------------------------------
__global__ __launch_bounds__(512, 2)
void gemm_qkv(const unsigned short* __restrict__ A,
              const unsigned short* __restrict__ BT,
              const float* __restrict__ b0,
              const float* __restrict__ b1,
              const float* __restrict__ b2,
              const float* __restrict__ beta,
              unsigned short* __restrict__ Cb)
{
    __shared__ unsigned short Ab[2][BM * BK];   // 2 x 32 KB
    __shared__ unsigned short Bb[2][BN * BK];   // 2 x 24 KB

    const int t   = threadIdx.x;
    const int ln  = t & 63;
    const int wv  = t >> 6;          // 0..7
    const int wr  = wv & 3;          // 4M -> 64-row slice
    const int wc  = wv >> 2;         // 2N -> 96-col slice
    const int m16 = ln & 15;
    const int g   = ln >> 4;         // 0..3
    const int sw  = m16 & 7;         // read-side swizzle key (row & 7)

    const int rowBase = blockIdx.y * BM;
    const int colBase = blockIdx.x * BN;

    // staging: thread t covers row (t>>3) of a 64-row chunk, 16B at a
    // pre-swizzled global col-chunk; LDS dest is linear (t*16B).
    const int sr  = t >> 3;                   // 0..63
    const int scx = (t & 7) ^ (sr & 7);       // global col-chunk to fetch
    const size_t gOff = (size_t)sr * DM + scx * 8;
    const int    ldOff = t * 8;               // shorts (t*16 bytes)

    f32x4 acc[4][6];
#pragma unroll
    for (int u = 0; u < 4; ++u)
#pragma unroll
        for (int v = 0; v < 6; ++v)
            acc[u][v] = (f32x4){0.f, 0.f, 0.f, 0.f};

    // prologue: stage K-tile 0 into buffer 0, full drain once
    {
        const unsigned short* a0 = A  + (size_t)rowBase * DM + gOff;
        const unsigned short* bt = BT + (size_t)colBase * DM + gOff;
#pragma unroll
        for (int cb = 0; cb < 3; ++cb)
            gld16(bt + (size_t)cb * 64 * DM, &Bb[0][cb * 4096 + ldOff]);
#pragma unroll
        for (int ca = 0; ca < 4; ++ca)
            gld16(a0 + (size_t)ca * 64 * DM, &Ab[0][ca * 4096 + ldOff]);
        asm volatile("s_waitcnt vmcnt(0)" ::: "memory");
        __builtin_amdgcn_s_barrier();
        __builtin_amdgcn_sched_barrier(0);
    }

    for (int kt = 0; kt < DM / BK; ++kt) {
        const int cur = kt & 1;
        const unsigned short* Ac = Ab[cur];
        const unsigned short* Bc = Bb[cur];
        unsigned short* An = Ab[cur ^ 1];
        unsigned short* Bn = Bb[cur ^ 1];
        const bool hn = (kt < DM / BK - 1);
        const unsigned short* aS = A  + (size_t)rowBase * DM + (kt + 1) * BK + gOff;
        const unsigned short* bS = BT + (size_t)colBase * DM + (kt + 1) * BK + gOff;

        // ---- kk = 0 fragment reads (10 x ds_read_b128) ----
        bf16x8 af0[4], bf0[6];
#pragma unroll
        for (int u = 0; u < 4; ++u)
            af0[u] = *(const bf16x8*)&Ac[(wr * 64 + u * 16 + m16) * BK + ((g ^ sw) * 8)];
#pragma unroll
        for (int v = 0; v < 6; ++v)
            bf0[v] = *(const bf16x8*)&Bc[(wc * 96 + v * 16 + m16) * BK + ((g ^ sw) * 8)];

        // ---- stage ALL of tile kt+1 now (7 loads, waited at end of iter) ----
        if (hn) {
            gld16(bS,                    &Bn[ldOff]);
            gld16(bS + (size_t)64 * DM,  &Bn[4096 + ldOff]);
            gld16(bS + (size_t)128 * DM, &Bn[2 * 4096 + ldOff]);
            gld16(aS,                    &An[ldOff]);
            gld16(aS + (size_t)64 * DM,  &An[4096 + ldOff]);
            gld16(aS + (size_t)128 * DM, &An[2 * 4096 + ldOff]);
            gld16(aS + (size_t)192 * DM, &An[3 * 4096 + ldOff]);
        }

        __builtin_amdgcn_s_setprio(1);
#pragma unroll
        for (int u = 0; u < 4; ++u)
#pragma unroll
            for (int v = 0; v < 6; ++v)
                acc[u][v] = __builtin_amdgcn_mfma_f32_16x16x32_bf16(
                    af0[u], bf0[v], acc[u][v], 0, 0, 0);
        __builtin_amdgcn_s_setprio(0);

        // ---- kk = 1 fragment reads ----
        bf16x8 af1[4], bf1[6];
#pragma unroll
        for (int u = 0; u < 4; ++u)
            af1[u] = *(const bf16x8*)&Ac[(wr * 64 + u * 16 + m16) * BK + (((4 | g) ^ sw) * 8)];
#pragma unroll
        for (int v = 0; v < 6; ++v)
            bf1[v] = *(const bf16x8*)&Bc[(wc * 96 + v * 16 + m16) * BK + (((4 | g) ^ sw) * 8)];

        __builtin_amdgcn_s_setprio(1);
#pragma unroll
        for (int u = 0; u < 4; ++u)
#pragma unroll
            for (int v = 0; v < 6; ++v)
                acc[u][v] = __builtin_amdgcn_mfma_f32_16x16x32_bf16(
                    af1[u], bf1[v], acc[u][v], 0, 0, 0);
        __builtin_amdgcn_s_setprio(0);

        if (hn)
            asm volatile("s_waitcnt vmcnt(0)" ::: "memory");
        __builtin_amdgcn_s_barrier();
        __builtin_amdgcn_sched_barrier(0);
    }

    // epilogue — same math as proven kernel; sec per fragment (wave-uniform).
    const int q4 = g * 4;
#pragma unroll
    for (int v = 0; v < 6; ++v) {
        const int col = colBase + wc * 96 + v * 16 + m16;
        const int sec = col >> 10;
        const int h   = (col >> 6) & (NHEAD - 1);
        const int dh  = col & 63;
        if (sec < 2) {
            const float bi = (sec == 0 ? b0 : b1)[col & (DM - 1)];
            const float sc = (sec == 0) ? 0.125f * __expf(-beta[h]) : 1.0f;
            unsigned short* base = Cb + (size_t)sec * MROWS * DM;
#pragma unroll
            for (int u = 0; u < 4; ++u)
#pragma unroll
                for (int r = 0; r < 4; ++r) {
                    const int row = rowBase + wr * 64 + u * 16 + q4 + r;
                    const int s = row >> 1, bb = row & 1;
                    const int z = bb * NHEAD + h;
                    base[((size_t)z * S_LEN + s) * DHEAD + dh] =
                        f2b((acc[u][v][r] + bi) * sc);
                }
        } else {
            unsigned short* vtb = Cb + (size_t)2 * MROWS * DM;
            const float bi = b2[col & (DM - 1)];
#pragma unroll
            for (int u = 0; u < 4; ++u) {
                const int row0 = rowBase + wr * 64 + u * 16 + q4;
                const int s0   = row0 >> 1;
                ushort2 p0, p1;
                p0.x = f2b(acc[u][v][0] + bi);   // bb=0, s0
                p0.y = f2b(acc[u][v][2] + bi);   // bb=0, s0+1
                p1.x = f2b(acc[u][v][1] + bi);   // bb=1, s0
                p1.y = f2b(acc[u][v][3] + bi);   // bb=1, s0+1
                *(ushort2*)(vtb + ((size_t)(h * DHEAD + dh) * S_LEN + s0)) = p0;
                *(ushort2*)(vtb + ((size_t)((NHEAD + h) * DHEAD + dh) * S_LEN + s0)) = p1;
            }
        }
    }
}

// ---------------------------------------------------------------------------
// R13 gemm_out: 128x128 tile, BK=64, 4 waves as 2x2 (wave tile 64x64 ->
// best reuse: 16 ds_read vs 32 MFMA per tile). Double-buffered 64 KB LDS ->
// 2 blocks/CU (inter-block TLP hides the per-tile drain). Same one-barrier
// counted schedule as gemm_qkv. Staging: 8 gld16/thread/tile (A 2 chunks +
// B 2 chunks, 2 half-chunks each at 256 threads).
// ---------------------------------------------------------------------------
__global__ __launch_bounds__(256, 2)
void gemm_out(const unsigned short* __restrict__ A,
              const unsigned short* __restrict__ BT,
              const float* __restrict__ bias,
              float* __restrict__ Cf)
{
    __shared__ unsigned short As[2][OM * BK];   // 2 x 16 KB
    __shared__ unsigned short Bs[2][ON * BK];   // 2 x 16 KB

    const int t  = threadIdx.x;
    const int wv = t >> 6, ln = t & 63;
    const int wr = wv >> 1, wc = wv & 1;        // 2x2, wave 64x64
    const int m16 = ln & 15, g = ln >> 4;
    const int sw  = m16 & 7;

    const int rowBase = blockIdx.y * OM;
    const int colBase = blockIdx.x * ON;

    // staging geometry (256 threads): rows sr and sr+32 of each 64-row chunk
    const int sr  = t >> 3;                   // 0..31  ((sr+32)&7 == sr&7)
    const int scx = (t & 7) ^ (sr & 7);
    const size_t gOff = (size_t)sr * DM + scx * 8;
    const int    ldOff = t * 8;               // + half*2048 within chunk

    f32x4 acc[4][4];
#pragma unroll
    for (int u = 0; u < 4; ++u)
#pragma unroll
        for (int v = 0; v < 4; ++v)
            acc[u][v] = (f32x4){0.f, 0.f, 0.f, 0.f};

    // prologue: stage K-tile 0
    {
        const unsigned short* a0 = A  + (size_t)rowBase * DM + gOff;
        const unsigned short* bt = BT + (size_t)colBase * DM + gOff;
#pragma unroll
        for (int ca = 0; ca < 2; ++ca)
#pragma unroll
            for (int hf = 0; hf < 2; ++hf)
                gld16(a0 + (size_t)(ca * 64 + hf * 32) * DM,
                      &As[0][ca * 4096 + hf * 2048 + ldOff]);
#pragma unroll
        for (int cb = 0; cb < 2; ++cb)
#pragma unroll
            for (int hf = 0; hf < 2; ++hf)
                gld16(bt + (size_t)(cb * 64 + hf * 32) * DM,
                      &Bs[0][cb * 4096 + hf * 2048 + ldOff]);
        asm volatile("s_waitcnt vmcnt(0)" ::: "memory");
        __builtin_amdgcn_s_barrier();
        __builtin_amdgcn_sched_barrier(0);
    }

    for (int kt = 0; kt < DM / BK; ++kt) {
        const int cur = kt & 1;
        const unsigned short* Ac = As[cur];
        const unsigned short* Bc = Bs[cur];
        unsigned short* An = As[cur ^ 1];
        unsigned short* Bn = Bs[cur ^ 1];
        const bool hn = (kt < DM / BK - 1);
        const unsigned short* aS = A  + (size_t)rowBase * DM + (kt + 1) * BK + gOff;
        const unsigned short* bS = BT + (size_t)colBase * DM + (kt + 1) * BK + gOff;

        bf16x8 af0[4], bf0[4];
#pragma unroll
        for (int u = 0; u < 4; ++u)
            af0[u] = *(const bf16x8*)&Ac[(wr * 64 + u * 16 + m16) * BK + ((g ^ sw) * 8)];
#pragma unroll
        for (int v = 0; v < 4; ++v)
            bf0[v] = *(const bf16x8*)&Bc[(wc * 64 + v * 16 + m16) * BK + ((g ^ sw) * 8)];

        if (hn) {
#pragma unroll
            for (int ca = 0; ca < 2; ++ca)
#pragma unroll
                for (int hf = 0; hf < 2; ++hf)
                    gld16(aS + (size_t)(ca * 64 + hf * 32) * DM,
                          &An[ca * 4096 + hf * 2048 + ldOff]);
#pragma unroll
            for (int cb = 0; cb < 2; ++cb)
#pragma unroll
                for (int hf = 0; hf < 2; ++hf)
                    gld16(bS + (size_t)(cb * 64 + hf * 32) * DM,
                          &Bn[cb * 4096 + hf * 2048 + ldOff]);
        }

        __builtin_amdgcn_s_setprio(1);
#pragma unroll
        for (int u = 0; u < 4; ++u)
#pragma unroll
            for (int v = 0; v < 4; ++v)
                acc[u][v] = __builtin_amdgcn_mfma_f32_16x16x32_bf16(
                    af0[u], bf0[v], acc[u][v], 0, 0, 0);
        __builtin_amdgcn_s_setprio(0);

        bf16x8 af1[4], bf1[4];
#pragma unroll
        for (int u = 0; u < 4; ++u)
            af1[u] = *(const bf16x8*)&Ac[(wr * 64 + u * 16 + m16) * BK + (((4 | g) ^ sw) * 8)];
#pragma unroll
        for (int v = 0; v < 4; ++v)
            bf1[v] = *(const bf16x8*)&Bc[(wc * 64 + v * 16 + m16) * BK + (((4 | g) ^ sw) * 8)];

        __builtin_amdgcn_s_setprio(1);
#pragma unroll
        for (int u = 0; u < 4; ++u)
#pragma unroll
            for (int v = 0; v < 4; ++v)
                acc[u][v] = __builtin_amdgcn_mfma_f32_16x16x32_bf16(
                    af1[u], bf1[v], acc[u][v], 0, 0, 0);
        __builtin_amdgcn_s_setprio(0);

        if (hn)
            asm volatile("s_waitcnt vmcnt(0)" ::: "memory");
        __builtin_amdgcn_s_barrier();
        __builtin_amdgcn_sched_barrier(0);
    }

    const int q4 = g * 4;
#pragma unroll
    for (int v = 0; v < 4; ++v) {
        const int col = colBase + wc * 64 + v * 16 + m16;
        const float bi = bias[col];
#pragma unroll
        for (int u = 0; u < 4; ++u)
#pragma unroll
            for (int r = 0; r < 4; ++r) {
                const int row = rowBase + wr * 64 + u * 16 + q4 + r;
                Cf[(size_t)row * DM + col] = acc[u][v][r] + bi;
            }
    }
}

// ---------------------------------------------------------------------------
// MFMA flash attention, windowed causal + sink — NO online max (R11-proven).
// Scores bounded (|s| <~ 6 after 0.125*exp(-beta) pre-scale) -> plain exp
// is safe in fp32. Sink: l0 = 1 = exp(0). Masked: exp(-1e30) == 0.
// q,k in (z,s,dh); V pre-transposed vt (z,dh,s). All staging b128.
// ---------------------------------------------------------------------------
__global__ __launch_bounds__(256, 4)
void attn_mfma(const unsigned short* __restrict__ q,
               const unsigned short* __restrict__ k,
               const unsigned short* __restrict__ vt,
               unsigned short* __restrict__ ao)
{
    __shared__ unsigned short Ks[64 * KP];   // [key][d]
    __shared__ unsigned short Vs[64 * KP];   // [dh][key]
    __shared__ float Ps[64][PPAD];           // [wave*16 + qrow][key]

    const int t   = threadIdx.x;
    const int wv  = t >> 6, ln = t & 63;
    const int m16 = ln & 15, g = ln >> 4;
    const int z   = blockIdx.y;
    const int q0  = blockIdx.x * 64;
    const size_t zbase = (size_t)z * S_LEN * DHEAD;

    const unsigned short* qrow = q + zbase + (size_t)(q0 + wv * 16 + m16) * DHEAD;
    bf16x8 qf0 = *(const bf16x8*)(qrow + g * 8);
    bf16x8 qf1 = *(const bf16x8*)(qrow + 32 + g * 8);

    f32x4 oacc[4];
#pragma unroll
    for (int v4 = 0; v4 < 4; ++v4) oacc[v4] = (f32x4){0.f, 0.f, 0.f, 0.f};
    float lr[4];
#pragma unroll
    for (int r = 0; r < 4; ++r) lr[r] = 1.f;   // sink: exp(0)

    for (int c = 0; c < 5; ++c) {
        const int kb = q0 - 256 + c * 64;
        if (kb < 0) continue;
        __syncthreads();

        // stage K [64][64] and V^T [64][64], b128 copies
#pragma unroll
        for (int i = 0; i < 2; ++i) {
            const int id  = t + 256 * i;
            const int row = id >> 3;
            const int co  = (id & 7) * 8;
            *(bf16x8*)&Ks[row * KP + co] =
                *(const bf16x8*)(k + zbase + (size_t)(kb + row) * DHEAD + co);
            *(bf16x8*)&Vs[row * KP + co] =
                *(const bf16x8*)(vt + ((size_t)z * DHEAD + row) * S_LEN + kb + co);
        }
        __syncthreads();

        // S = Q K^T
        f32x4 sacc[4];
#pragma unroll
        for (int v4 = 0; v4 < 4; ++v4) {
            sacc[v4] = (f32x4){0.f, 0.f, 0.f, 0.f};
            bf16x8 kf0 = *(const bf16x8*)&Ks[(v4 * 16 + m16) * KP + g * 8];
            sacc[v4] = __builtin_amdgcn_mfma_f32_16x16x32_bf16(qf0, kf0, sacc[v4], 0, 0, 0);
            bf16x8 kf1 = *(const bf16x8*)&Ks[(v4 * 16 + m16) * KP + 32 + g * 8];
            sacc[v4] = __builtin_amdgcn_mfma_f32_16x16x32_bf16(qf1, kf1, sacc[v4], 0, 0, 0);
        }

        // mask + exp + row-sum (no max): P -> LDS
        const bool mhi = (c == 4), mlo = (c == 0);
#pragma unroll
        for (int r = 0; r < 4; ++r) {
            const int ig = q0 + wv * 16 + g * 4 + r;
            float rsum = 0.f;
#pragma unroll
            for (int v4 = 0; v4 < 4; ++v4) {
                const int jg = kb + v4 * 16 + m16;
                float x = sacc[v4][r];
                const bool valid = (!mhi || jg <= ig) && (!mlo || jg >= ig - (WIN - 1));
                x = valid ? x : -1e30f;
                const float pp = __expf(x);     // masked -> exactly 0
                Ps[wv * 16 + g * 4 + r][v4 * 16 + m16] = pp;
                rsum += pp;
            }
#pragma unroll
            for (int off = 1; off < 16; off <<= 1)
                rsum += __shfl_xor(rsum, off, 64);
            lr[r] += rsum;
        }
        __syncthreads();

        // O += P V
        const float* prow = &Ps[wv * 16 + m16][0];
        bf16x8 pf0 = pack8(*(const float4*)(prow + g * 8),
                           *(const float4*)(prow + g * 8 + 4));
        bf16x8 pf1 = pack8(*(const float4*)(prow + 32 + g * 8),
                           *(const float4*)(prow + 32 + g * 8 + 4));
#pragma unroll
        for (int v4 = 0; v4 < 4; ++v4) {
            bf16x8 vf0 = *(const bf16x8*)&Vs[(v4 * 16 + m16) * KP + g * 8];
            oacc[v4] = __builtin_amdgcn_mfma_f32_16x16x32_bf16(pf0, vf0, oacc[v4], 0, 0, 0);
            bf16x8 vf1 = *(const bf16x8*)&Vs[(v4 * 16 + m16) * KP + 32 + g * 8];
            oacc[v4] = __builtin_amdgcn_mfma_f32_16x16x32_bf16(pf1, vf1, oacc[v4], 0, 0, 0);
        }
    }

    const int bb = z >> 4, h = z & 15;
#pragma unroll
    for (int r = 0; r < 4; ++r) {
        const int ig  = q0 + wv * 16 + g * 4 + r;
        const float inv = 1.f / lr[r];
#pragma unroll
        for (int v4 = 0; v4 < 4; ++v4)
            ao[(size_t)(ig * BATCH + bb) * DM + h * DHEAD + v4 * 16 + m16] =
                f2b(oacc[v4][r] * inv);
    }
}

// ---------------------------------------------------------------------------
extern "C" void kernel_launch(void* const* d_in, const int* in_sizes, int n_in,
                              void* d_out, int out_size, void* d_ws, size_t ws_size,
                              hipStream_t stream)
{
    const float* x    = (const float*)d_in[0];
    const float* beta = (const float*)d_in[1];
    const float* Wq   = (const float*)d_in[2];
    const float* bq   = (const float*)d_in[3];
    const float* Wk   = (const float*)d_in[4];
    const float* bk   = (const float*)d_in[5];
    const float* Wv   = (const float*)d_in[6];
    const float* bv   = (const float*)d_in[7];
    const float* Wo   = (const float*)d_in[8];
    const float* bo   = (const float*)d_in[9];
    float* out = (float*)d_out;

    unsigned short* w = (unsigned short*)d_ws;
    const size_t seg = (size_t)MROWS * DM;      // 4M elems
    unsigned short* qb  = w;                    // q (z,s,dh)
    unsigned short* kb  = w + seg;              // k (z,s,dh)
    unsigned short* vtb = w + 2 * seg;          // v^T (z,dh,s) -- direct from QKV
    unsigned short* ab  = w + 3 * seg;          // attn out, row-major
    unsigned short* xb  = w + 4 * seg;          // x bf16
    unsigned short* wtq = w + 5 * seg;          // WqT|WkT|WvT|WoT contiguous
    unsigned short* wtk = wtq + (size_t)DM * DM;
    unsigned short* wtv = wtk + (size_t)DM * DM;
    unsigned short* wto = wtv + (size_t)DM * DM;

    cvtx<<<4096, 256, 0, stream>>>(x, xb);
    twcvt4<<<dim3(32, 32, 4), 256, 0, stream>>>(Wq, Wk, Wv, Wo, wtq, wtk, wtv, wto);

    // fused Q+K+V projection: 256x192 tiles -> 16x16 = 256 blocks (1/CU)
    gemm_qkv<<<dim3(3072 / BN, MROWS / BM), 512, 0, stream>>>(
        xb, wtq, bq, bk, bv, beta, qb);

    attn_mfma<<<dim3(S_LEN / 64, BATCH * NHEAD), 256, 0, stream>>>(qb, kb, vtb, ab);

    // output projection: 128x128 tiles -> 8x32 = 256 blocks (2/CU)
    gemm_out<<<dim3(DM / ON, MROWS / OM), 256, 0, stream>>>(ab, wto, bo, out);
}